// Round 1
// baseline (1930.697 us; speedup 1.0000x reference)
//
#include <hip/hip_runtime.h>
#include <math.h>

#define NB   256
#define ND   63
#define NN   3969        // 63*63
#define MLc  3
#define KSc  7
#define MIDc 32

__device__ __forceinline__ float gelu_f(float v){
    return 0.5f * v * (1.0f + erff(v * 0.70710678118654752440f));
}

union F4 { float4 v; float a[4]; };

// ---------------- DFT tables (64x64 padded, row/col 63 zeroed) + acc reset ----
__global__ void k_tables(float* __restrict__ Fr, float* __restrict__ Fi, float* __restrict__ acc){
    int idx = blockIdx.x * blockDim.x + threadIdx.x;
    if (idx < 4096){
        int r = idx >> 6, c = idx & 63;
        float vr = 0.f, vi = 0.f;
        if (r < 63 && c < 63){
            int m = (r * c) % 63;
            float ang = 6.283185307179586f * (float)m / 63.0f;
            vr = cosf(ang); vi = -sinf(ang);
        }
        Fr[idx] = vr; Fi[idx] = vi;
    }
    if (idx == 0) acc[0] = 0.f;
}

// ---------------- hypernet: per-sample 9->100(gelu)->147, twice --------------
__global__ void k_hyper(const float* __restrict__ kA,
                        const float* __restrict__ w1a, const float* __restrict__ b1a,
                        const float* __restrict__ w2a, const float* __restrict__ b2a,
                        const float* __restrict__ w1b, const float* __restrict__ b1b,
                        const float* __restrict__ w2b, const float* __restrict__ b2b,
                        float* __restrict__ out1, float* __restrict__ out2){
    __shared__ float a[9];
    __shared__ float hid[100];
    int b = blockIdx.x, tid = threadIdx.x;
    if (tid < 9) a[tid] = kA[b*9 + tid];
    __syncthreads();
    if (tid < 100){
        float s = b1a[tid];
        #pragma unroll
        for (int i = 0; i < 9; i++) s = fmaf(a[i], w1a[i*100 + tid], s);
        hid[tid] = gelu_f(s);
    }
    __syncthreads();
    if (tid < 147){
        float s = b2a[tid];
        for (int k = 0; k < 100; k++) s = fmaf(hid[k], w2a[k*147 + tid], s);
        out1[b*147 + tid] = s;
    }
    __syncthreads();
    if (tid < 100){
        float s = b1b[tid];
        #pragma unroll
        for (int i = 0; i < 9; i++) s = fmaf(a[i], w1b[i*100 + tid], s);
        hid[tid] = gelu_f(s);
    }
    __syncthreads();
    if (tid < 147){
        float s = b2b[tid];
        for (int k = 0; k < 100; k++) s = fmaf(hid[k], w2b[k*147 + tid], s);
        out2[b*147 + tid] = s;
    }
}

// ---------------- generic ConvTranspose2d (torch semantics, w [Cin,Cout,3,3]) -
__global__ void k_ctrans(const float* __restrict__ in, const float* __restrict__ w,
                         const float* __restrict__ bias, float* __restrict__ out,
                         int Cin, int Cout, int Hin, int Hout, int stride, int pad,
                         int total, int doGelu){
    int idx = blockIdx.x * blockDim.x + threadIdx.x;
    if (idx >= total) return;
    int ox = idx % Hout; int t = idx / Hout;
    int oy = t % Hout;  t /= Hout;
    int co = t % Cout;  int b = t / Cout;
    float s = bias[co];
    for (int ky = 0; ky < 3; ky++){
        int ty = oy + pad - ky;
        if (ty < 0 || (ty % stride)) continue;
        int iy = ty / stride; if (iy >= Hin) continue;
        for (int kx = 0; kx < 3; kx++){
            int tx = ox + pad - kx;
            if (tx < 0 || (tx % stride)) continue;
            int ix = tx / stride; if (ix >= Hin) continue;
            const float* ip = in + ((size_t)b*Cin)*Hin*Hin + iy*Hin + ix;
            float acc = 0.f;
            for (int ci = 0; ci < Cin; ci++)
                acc = fmaf(ip[ci*Hin*Hin], w[((ci*Cout + co)*3 + ky)*3 + kx], acc);
            s += acc;
        }
    }
    if (doGelu) s = gelu_f(s);
    out[idx] = s;
}

// ---------------- build spectral multiplier v (stride-64 rows) ---------------
__global__ void k_buildv(const float* __restrict__ h5, float* __restrict__ vr,
                         float* __restrict__ vi, int total){
    int idx = blockIdx.x * blockDim.x + threadIdx.x;
    if (idx >= total) return;
    int i = idx % NN; int b = idx / NN;
    int ky = i / ND, kx = i % ND;
    const float* hb = h5 + (size_t)b * 2 * NN;   // [2,63,63] flat, reinterp as (re,im) pairs
    float re, im;
    if (kx <= 31){ int o = 2*i; re = hb[o]; im = hb[o+1]; }
    else {
        int sy = (ND - ky) % ND; int sx = ND - kx;
        int o = 2*(sy*ND + sx); re = hb[o]; im = -hb[o+1];
    }
    const float sc = 1.0f / 3969.0f;
    vr[(size_t)b*4032 + ky*64 + kx] = re * sc;
    vi[(size_t)b*4032 + ky*64 + kx] = im * sc;
}

// ---------------- residual: r = f - conv3x3(pad_bc(x), kA) -------------------
__global__ void k_residual(const float* __restrict__ x, const float* __restrict__ f,
                           const float* __restrict__ kA, float* __restrict__ r){
    int idx = blockIdx.x * blockDim.x + threadIdx.x;
    if (idx >= NB * NN) return;
    int i = idx % NN; int b = idx / NN;
    int y = i / ND, xx = i % ND;
    const float* ka = kA + b*9;
    const float* xb = x + (size_t)b*NN;
    float s = 0.f;
    #pragma unroll
    for (int dy = 0; dy < 3; dy++){
        int u = y + dy;
        #pragma unroll
        for (int dx = 0; dx < 3; dx++){
            int v = xx + dx;
            float p;
            if (u == 64 || v == 64)      p = 1.0f;
            else if (u == 0 || v == 0)   p = 0.0f;
            else                         p = xb[(u-1)*ND + (v-1)];
            s = fmaf(p, ka[dy*3 + dx], s);
        }
    }
    r[idx] = f[idx] - s;
}

// ---------------- fused smoother: x += conv7(conv7(residual(x),w1),w2) -------
__global__ __launch_bounds__(512) void k_smoother(const float* __restrict__ f,
                                                  const float* __restrict__ kA,
                                                  const float* __restrict__ w1,
                                                  const float* __restrict__ w2,
                                                  float* __restrict__ x){
    __shared__ float rs[63*70];     // 3-col halo left, 4-col halo right
    __shared__ float tc[63*70];
    __shared__ float w1s[147], w2s[147];
    int b = blockIdx.x, tid = threadIdx.x;
    if (tid < 147){ w1s[tid] = w1[b*147 + tid]; w2s[tid] = w2[b*147 + tid]; }
    for (int i = tid; i < 63*70; i += 512){ rs[i] = 0.f; tc[i] = 0.f; }
    float* xg = x + (size_t)b*NN;
    const float* fg = f + (size_t)b*NN;
    float ka[9];
    #pragma unroll
    for (int i = 0; i < 9; i++) ka[i] = kA[b*9 + i];
    __syncthreads();
    // residual into rs interior
    for (int i = tid; i < NN; i += 512){
        int y = i / ND, xx = i % ND;
        float s = 0.f;
        #pragma unroll
        for (int dy = 0; dy < 3; dy++){
            int u = y + dy;
            #pragma unroll
            for (int dx = 0; dx < 3; dx++){
                int v = xx + dx;
                float p;
                if (u == 64 || v == 64)    p = 1.0f;
                else if (u == 0 || v == 0) p = 0.0f;
                else                       p = xg[(u-1)*ND + (v-1)];
                s = fmaf(p, ka[dy*3 + dx], s);
            }
        }
        rs[y*70 + 3 + xx] = fg[i] - s;
    }
    __syncthreads();
    int task = tid;
    bool active = task < 504;           // 63 rows * 8 col-tiles
    int xt = task & 7, y0 = task >> 3;
    int x0 = xt * 8;
    float acc2[8] = {0,0,0,0,0,0,0,0};
    for (int c = 0; c < 3; c++){
        if (active){
            float a1[8] = {0,0,0,0,0,0,0,0};
            for (int dy = 0; dy < 7; dy++){
                int ry = y0 + dy - 3;
                if (ry < 0 || ry >= 63) continue;
                float win[14];
                #pragma unroll
                for (int t = 0; t < 14; t++) win[t] = rs[ry*70 + x0 + t];
                #pragma unroll
                for (int dx = 0; dx < 7; dx++){
                    float wv = w1s[c*49 + dy*7 + dx];
                    #pragma unroll
                    for (int t = 0; t < 8; t++) a1[t] = fmaf(wv, win[t + dx], a1[t]);
                }
            }
            int nw = 63 - x0; if (nw > 8) nw = 8;
            for (int t = 0; t < nw; t++) tc[y0*70 + 3 + x0 + t] = a1[t];
        }
        __syncthreads();
        if (active){
            for (int dy = 0; dy < 7; dy++){
                int ry = y0 + dy - 3;
                if (ry < 0 || ry >= 63) continue;
                float win[14];
                #pragma unroll
                for (int t = 0; t < 14; t++) win[t] = tc[ry*70 + x0 + t];
                #pragma unroll
                for (int dx = 0; dx < 7; dx++){
                    float wv = w2s[c*49 + dy*7 + dx];
                    #pragma unroll
                    for (int t = 0; t < 8; t++) acc2[t] = fmaf(wv, win[t + dx], acc2[t]);
                }
            }
        }
        __syncthreads();
    }
    if (active){
        int nw = 63 - x0; if (nw > 8) nw = 8;
        float* xo = xg + y0*ND + x0;
        for (int t = 0; t < nw; t++) xo[t] += acc2[t];
    }
}

// ---------------- fused spectral correction: x += Re(F*((F r F).v)F*) --------
// One block per sample, 256 threads, 4x4 register tiles, 64KB LDS (4 planes 64x64).
__global__ __launch_bounds__(256) void k_hcorrect(const float* __restrict__ Frg,
                                                  const float* __restrict__ Fig,
                                                  const float* __restrict__ r,
                                                  const float* __restrict__ vrg,
                                                  const float* __restrict__ vig,
                                                  float* __restrict__ x){
    __shared__ float sA[2*4096];   // plane0: r then Mr ; plane1: Mi
    __shared__ float sB[2*4096];   // plane0: Ttr then Ptr ; plane1: Tti then Pti
    int b = blockIdx.x, tid = threadIdx.x;
    int kt = tid >> 4, ct = tid & 15;
    int k0 = kt * 4, c0 = ct * 4;
    const float4* F4r = (const float4*)Frg;
    const float4* F4i = (const float4*)Fig;
    float4* A40 = (float4*)sA;          float4* A41 = (float4*)(sA + 4096);
    float4* B40 = (float4*)sB;          float4* B41 = (float4*)(sB + 4096);
    const float* rg = r + (size_t)b*NN;

    for (int i = tid; i < NN; i += 256) sA[(i/ND)*64 + (i%ND)] = rg[i];
    for (int i = tid; i < 64; i += 256) sA[i*64 + 63] = 0.f;     // zero col 63 of r plane
    __syncthreads();

    // Phase A: T = F r  -> store transposed Tt[n][k] in sB
    {
        float tr[4][4] = {}, ti[4][4] = {};
        for (int m = 0; m < 63; m++){
            F4 fr, fi, rv;
            fr.v = F4r[m*16 + kt]; fi.v = F4i[m*16 + kt];
            rv.v = A40[m*16 + ct];
            #pragma unroll
            for (int i = 0; i < 4; i++)
                #pragma unroll
                for (int j = 0; j < 4; j++){
                    tr[i][j] = fmaf(fr.a[i], rv.a[j], tr[i][j]);
                    ti[i][j] = fmaf(fi.a[i], rv.a[j], ti[i][j]);
                }
        }
        #pragma unroll
        for (int j = 0; j < 4; j++){
            F4 sv, si;
            #pragma unroll
            for (int i = 0; i < 4; i++){ sv.a[i] = tr[i][j]; si.a[i] = ti[i][j]; }
            B40[(c0 + j)*16 + kt] = sv.v;
            B41[(c0 + j)*16 + kt] = si.v;
        }
    }
    __syncthreads();

    // Phase B: R = T F ; C: M = R .* v  -> store M[k][l] in sA
    {
        float Rr[4][4] = {}, Ri[4][4] = {};
        for (int n = 0; n < 63; n++){
            F4 ar, ai, fr, fi;
            ar.v = B40[n*16 + kt]; ai.v = B41[n*16 + kt];
            fr.v = F4r[n*16 + ct]; fi.v = F4i[n*16 + ct];
            #pragma unroll
            for (int i = 0; i < 4; i++)
                #pragma unroll
                for (int j = 0; j < 4; j++){
                    Rr[i][j] = fmaf(ar.a[i], fr.a[j], Rr[i][j]);
                    Rr[i][j] = fmaf(-ai.a[i], fi.a[j], Rr[i][j]);
                    Ri[i][j] = fmaf(ar.a[i], fi.a[j], Ri[i][j]);
                    Ri[i][j] = fmaf(ai.a[i], fr.a[j], Ri[i][j]);
                }
        }
        const float4* v4r = (const float4*)(vrg + (size_t)b*4032);
        const float4* v4i = (const float4*)(vig + (size_t)b*4032);
        #pragma unroll
        for (int i = 0; i < 4; i++){
            int k = k0 + i;
            int kk = k < 63 ? k : 62;
            F4 wr, wi, mr, mi;
            wr.v = v4r[kk*16 + ct]; wi.v = v4i[kk*16 + ct];
            #pragma unroll
            for (int j = 0; j < 4; j++){
                mr.a[j] = Rr[i][j]*wr.a[j] - Ri[i][j]*wi.a[j];
                mi.a[j] = Rr[i][j]*wi.a[j] + Ri[i][j]*wr.a[j];
            }
            A40[k*16 + ct] = mr.v;
            A41[k*16 + ct] = mi.v;
        }
    }
    __syncthreads();

    // Phase D: P = conj(F) M -> store transposed Pt[l][k] in sB
    {
        float Pr[4][4] = {}, Pi[4][4] = {};
        for (int n = 0; n < 63; n++){
            F4 fr, fi, mr, mi;
            fr.v = F4r[n*16 + kt]; fi.v = F4i[n*16 + kt];
            mr.v = A40[n*16 + ct]; mi.v = A41[n*16 + ct];
            #pragma unroll
            for (int i = 0; i < 4; i++)
                #pragma unroll
                for (int j = 0; j < 4; j++){
                    Pr[i][j] = fmaf(fr.a[i], mr.a[j], Pr[i][j]);
                    Pr[i][j] = fmaf(fi.a[i], mi.a[j], Pr[i][j]);
                    Pi[i][j] = fmaf(fr.a[i], mi.a[j], Pi[i][j]);
                    Pi[i][j] = fmaf(-fi.a[i], mr.a[j], Pi[i][j]);
                }
        }
        #pragma unroll
        for (int j = 0; j < 4; j++){
            F4 sv, si;
            #pragma unroll
            for (int i = 0; i < 4; i++){ sv.a[i] = Pr[i][j]; si.a[i] = Pi[i][j]; }
            B40[(c0 + j)*16 + kt] = sv.v;
            B41[(c0 + j)*16 + kt] = si.v;
        }
    }
    __syncthreads();

    // Phase E: y = Re(P conj(F)) ; x += y
    {
        float yv[4][4] = {};
        for (int l = 0; l < 63; l++){
            F4 pr, pi, fr, fi;
            pr.v = B40[l*16 + kt]; pi.v = B41[l*16 + kt];
            fr.v = F4r[l*16 + ct]; fi.v = F4i[l*16 + ct];
            #pragma unroll
            for (int i = 0; i < 4; i++)
                #pragma unroll
                for (int j = 0; j < 4; j++){
                    yv[i][j] = fmaf(pr.a[i], fr.a[j], yv[i][j]);
                    yv[i][j] = fmaf(pi.a[i], fi.a[j], yv[i][j]);
                }
        }
        float* xg = x + (size_t)b*NN;
        #pragma unroll
        for (int i = 0; i < 4; i++){
            int p = k0 + i;
            if (p < 63){
                #pragma unroll
                for (int j = 0; j < 4; j++){
                    int q = c0 + j;
                    if (q < 63) xg[p*ND + q] += yv[i][j];
                }
            }
        }
    }
}

// ---------------- norm reduction --------------------------------------------
__global__ void k_norm(const float* __restrict__ r, float* __restrict__ acc){
    float s = 0.f;
    int stride = gridDim.x * blockDim.x;
    for (int i = blockIdx.x * blockDim.x + threadIdx.x; i < NB*NN; i += stride){
        float v = r[i]; s = fmaf(v, v, s);
    }
    #pragma unroll
    for (int off = 32; off > 0; off >>= 1) s += __shfl_down(s, off, 64);
    __shared__ float red[4];
    int lane = threadIdx.x & 63, w = threadIdx.x >> 6;
    if (lane == 0) red[w] = s;
    __syncthreads();
    if (threadIdx.x == 0) atomicAdd(acc, red[0] + red[1] + red[2] + red[3]);
}

__global__ void k_final(const float* __restrict__ acc, float* __restrict__ out){
    if (threadIdx.x == 0 && blockIdx.x == 0) out[0] = sqrtf(acc[0]) * (1.0f/256.0f);
}

// ---------------- host ------------------------------------------------------
extern "C" void kernel_launch(void* const* d_in, const int* in_sizes, int n_in,
                              void* d_out, int out_size, void* d_ws, size_t ws_size,
                              hipStream_t stream){
    const float* x0     = (const float*)d_in[0];
    const float* f      = (const float*)d_in[1];
    const float* kA     = (const float*)d_in[2];
    const float* fc1_w1 = (const float*)d_in[3];
    const float* fc1_b1 = (const float*)d_in[4];
    const float* fc1_w2 = (const float*)d_in[5];
    const float* fc1_b2 = (const float*)d_in[6];
    const float* fc2_w1 = (const float*)d_in[7];
    const float* fc2_b1 = (const float*)d_in[8];
    const float* fc2_w2 = (const float*)d_in[9];
    const float* fc2_b2 = (const float*)d_in[10];
    const float* ct1_w  = (const float*)d_in[11];
    const float* ct1_b  = (const float*)d_in[12];
    const float* ct2_w  = (const float*)d_in[13];
    const float* ct2_b  = (const float*)d_in[14];
    const float* ct3_w  = (const float*)d_in[15];
    const float* ct3_b  = (const float*)d_in[16];
    const float* ct4_w  = (const float*)d_in[17];
    const float* ct4_b  = (const float*)d_in[18];
    const float* ct5_w  = (const float*)d_in[19];
    const float* ct5_b  = (const float*)d_in[20];
    float* out = (float*)d_out;

    float* ws = (float*)d_ws;
    size_t off = 0;
    auto take = [&](size_t n){ float* p = ws + off; off += (n + 63) & ~(size_t)63; return p; };
    float* Fr  = take(4096);
    float* Fi  = take(4096);
    float* acc = take(64);
    float* w1b = take((size_t)NB*147);
    float* w2b = take((size_t)NB*147);
    float* xb  = take((size_t)NB*NN);
    float* rb  = take((size_t)NB*NN);
    float* vr  = take((size_t)NB*4032);
    float* vi  = take((size_t)NB*4032);
    float* c1  = take((size_t)NB*MIDc*5*5);
    float* c2  = take((size_t)NB*MIDc*9*9);
    float* c3  = take((size_t)NB*MIDc*17*17);
    float* c4  = take((size_t)NB*MIDc*33*33);
    float* c5  = take((size_t)NB*2*NN);
    (void)ws_size; (void)in_sizes; (void)n_in; (void)out_size;

    k_tables<<<16, 256, 0, stream>>>(Fr, Fi, acc);
    k_hyper<<<NB, 192, 0, stream>>>(kA, fc1_w1, fc1_b1, fc1_w2, fc1_b2,
                                    fc2_w1, fc2_b1, fc2_w2, fc2_b2, w1b, w2b);
    hipMemcpyAsync(xb, x0, (size_t)NB*NN*sizeof(float), hipMemcpyDeviceToDevice, stream);

    int t1 = NB*MIDc*5*5;
    k_ctrans<<<(t1+255)/256, 256, 0, stream>>>(kA, ct1_w, ct1_b, c1, 1,    MIDc, 3,  5,  2, 1, t1, 1);
    int t2 = NB*MIDc*9*9;
    k_ctrans<<<(t2+255)/256, 256, 0, stream>>>(c1, ct2_w, ct2_b, c2, MIDc, MIDc, 5,  9,  2, 1, t2, 1);
    int t3 = NB*MIDc*17*17;
    k_ctrans<<<(t3+255)/256, 256, 0, stream>>>(c2, ct3_w, ct3_b, c3, MIDc, MIDc, 9,  17, 2, 1, t3, 1);
    int t4 = NB*MIDc*33*33;
    k_ctrans<<<(t4+255)/256, 256, 0, stream>>>(c3, ct4_w, ct4_b, c4, MIDc, MIDc, 17, 33, 2, 1, t4, 1);
    int t5 = NB*2*NN;
    k_ctrans<<<(t5+255)/256, 256, 0, stream>>>(c4, ct5_w, ct5_b, c5, MIDc, 2,    33, 63, 2, 2, t5, 0);

    k_buildv<<<(NB*NN+255)/256, 256, 0, stream>>>(c5, vr, vi, NB*NN);

    for (int it = 0; it < 5; it++){
        k_smoother<<<NB, 512, 0, stream>>>(f, kA, w1b, w2b, xb);
        k_residual<<<(NB*NN+255)/256, 256, 0, stream>>>(xb, f, kA, rb);
        k_hcorrect<<<NB, 256, 0, stream>>>(Fr, Fi, rb, vr, vi, xb);
    }
    k_residual<<<(NB*NN+255)/256, 256, 0, stream>>>(xb, f, kA, rb);
    k_norm<<<256, 256, 0, stream>>>(rb, acc);
    k_final<<<1, 64, 0, stream>>>(acc, out);
}